// Round 9
// baseline (94.617 us; speedup 1.0000x reference)
//
#include <hip/hip_runtime.h>
#include <cstdint>
#include <cstddef>

typedef __bf16 bf16_t;
typedef __bf16 bf16x4 __attribute__((ext_vector_type(4)));
typedef __bf16 bf16x8 __attribute__((ext_vector_type(8)));
typedef float f32x4 __attribute__((ext_vector_type(4)));

#define M_DIM 4096
#define K_DIM 2048
#define N_DIM 2048

// ---- GEMM geometry: m97 template. 128x128, BK=64, single 32KiB buffer ----
#define BM 128
#define BN 128
#define BK 64
#define KT (K_DIM / BK)        // 32 K-steps
#define A_EL (BM * BK)         // 8192 bf16 (16 KiB)
#define B_EL (BN * BK)         // 8192 bf16 (16 KiB)
#define B_OFF A_EL

#define ZCAP 64                // spikes kept per row; overflow -> dense path

#define MFMA16(a, b, c) \
  __builtin_amdgcn_mfma_f32_16x16x32_bf16((a), (b), (c), 0, 0, 0)

__device__ __forceinline__ void gload_lds16(const bf16_t* g, bf16_t* l) {
  __builtin_amdgcn_global_load_lds(
      (const __attribute__((address_space(1))) void*)g,
      (__attribute__((address_space(3))) void*)l, 16, 0, 0);
}

// ---------------------------------------------------------------------------
// Merged prepass: [0,4096) inputs f32->bf16; [4096,5120) transpose fwd_w;
// [5120,6144) scan Z into (cnt, idx, val) per row.
// ---------------------------------------------------------------------------
__global__ __launch_bounds__(256) void prepass_all(
    const float* __restrict__ inputs, const float* __restrict__ fwd_w,
    const float* __restrict__ Z, bf16_t* __restrict__ abf,
    bf16_t* __restrict__ wT, int* __restrict__ zcnt, int* __restrict__ zidx,
    float* __restrict__ zval) {
  __shared__ float tile[64][65];
  const int b = blockIdx.x;
  const int t = threadIdx.x;

  if (b < 4096) {  // ---- convert_a ----
    const size_t base = ((size_t)b * 256 + t) * 8;
    const float4 v0 = *reinterpret_cast<const float4*>(inputs + base);
    const float4 v1 = *reinterpret_cast<const float4*>(inputs + base + 4);
    bf16x8 o;
    o[0] = (bf16_t)v0.x; o[1] = (bf16_t)v0.y;
    o[2] = (bf16_t)v0.z; o[3] = (bf16_t)v0.w;
    o[4] = (bf16_t)v1.x; o[5] = (bf16_t)v1.y;
    o[6] = (bf16_t)v1.z; o[7] = (bf16_t)v1.w;
    *reinterpret_cast<bf16x8*>(abf + base) = o;
  } else if (b < 5120) {  // ---- transpose_w ----
    const int bb = b - 4096;
    const int n0 = (bb & 31) * 64;
    const int k0 = (bb >> 5) * 64;
#pragma unroll
    for (int p = 0; p < 4; ++p) {
      const int r = p * 16 + (t >> 4);
      const int c = (t & 15) * 4;
      const float4 v = *reinterpret_cast<const float4*>(
          &fwd_w[(size_t)(k0 + r) * N_DIM + n0 + c]);
      tile[r][c + 0] = v.x;
      tile[r][c + 1] = v.y;
      tile[r][c + 2] = v.z;
      tile[r][c + 3] = v.w;
    }
    __syncthreads();
#pragma unroll
    for (int p = 0; p < 4; ++p) {
      const int n = p * 16 + (t >> 4);
      const int c = (t & 15) * 4;
      bf16x4 o;
      o[0] = (bf16_t)tile[c + 0][n];
      o[1] = (bf16_t)tile[c + 1][n];
      o[2] = (bf16_t)tile[c + 2][n];
      o[3] = (bf16_t)tile[c + 3][n];
      *reinterpret_cast<bf16x4*>(&wT[(size_t)(n0 + n) * K_DIM + k0 + c]) = o;
    }
  } else {  // ---- scan_z ----
    const int row = (b - 5120) * 4 + (t >> 6);
    const int lane = t & 63;
    const float* zr = Z + (size_t)row * N_DIM;
    int local = 0;
#pragma unroll
    for (int c = 0; c < 32; c += 4) {
      const f32x4 v = *reinterpret_cast<const f32x4*>(zr + lane * 32 + c);
#pragma unroll
      for (int e = 0; e < 4; ++e) local += (v[e] != 0.0f) ? 1 : 0;
    }
    int pre = local;
#pragma unroll
    for (int d = 1; d < 64; d <<= 1) {
      const int up = __shfl_up(pre, d, 64);
      if (lane >= d) pre += up;
    }
    const int total = __shfl(pre, 63, 64);
    if (lane == 0) zcnt[row] = total;
    if (total > 0 && total <= ZCAP) {
      int wpos = pre - local;
      int* zi = zidx + (size_t)row * ZCAP;
      float* zv = zval + (size_t)row * ZCAP;
      for (int c = lane * 32; c < lane * 32 + 32; ++c) {
        const float v = zr[c];
        if (v != 0.0f) {
          zi[wpos] = c;
          zv[wpos] = v;
          ++wpos;
        }
      }
    }
  }
}

// ---------------------------------------------------------------------------
// Pure GEMM (m97 template): cur = abf @ wT^T, single-buffer LDS, 2 syncs/step,
// 3 blocks/CU. Output written as bf16 via LDS transpose (coalesced).
// ---------------------------------------------------------------------------
__global__ __launch_bounds__(256, 3) void gemm_cur(
    const bf16_t* __restrict__ A, const bf16_t* __restrict__ W,
    bf16_t* __restrict__ cur) {
  __shared__ __align__(16) bf16_t lds[A_EL + B_EL];  // 32 KiB

  const int tid = threadIdx.x;
  const int lane = tid & 63;
  const int wave = tid >> 6;   // 0..3
  const int wm = wave >> 1;    // 0..1
  const int wn = wave & 1;     // 0..1
  const int l15 = lane & 15;
  const int l4 = lane >> 4;

  // T1: XCD swizzle (512 blocks, bijective)
  const int bid = blockIdx.x;
  const int swz = (bid & 7) * 64 + (bid >> 3);
  const int m0 = (swz >> 4) * BM;  // 32 m-tiles
  const int n0 = (swz & 15) * BN;  // 16 n-tiles

  // ---- staging (pre-swizzled global source, linear LDS dest; rule 21) ----
  const int lr = lane >> 3;        // 0..7
  const int sg = (lane & 7) ^ lr;  // swizzled 16B-slot (8 slots per 128B row)
  const bf16_t* aSrc[4];
  const bf16_t* bSrc[4];
  int aDst[4], bDst[4];
#pragma unroll
  for (int i = 0; i < 4; ++i) {
    const int r = wave * 32 + i * 8 + lr;  // rows 0..127
    aSrc[i] = A + (size_t)(m0 + r) * K_DIM + sg * 8;
    aDst[i] = r * BK + (lane & 7) * 8;
    bSrc[i] = W + (size_t)(n0 + r) * K_DIM + sg * 8;
    bDst[i] = B_OFF + r * BK + (lane & 7) * 8;
  }

  // ---- swizzled fragment read bases ----
  int aBase[2], bBase[2];
#pragma unroll
  for (int ks = 0; ks < 2; ++ks) {
    const int phys = (l4 + ks * 4) ^ (l15 & 7);
    aBase[ks] = (wm * 64 + l15) * BK + phys * 8;
    bBase[ks] = B_OFF + (wn * 64 + l15) * BK + phys * 8;
  }

  f32x4 acc[4][4];
#pragma unroll
  for (int i = 0; i < 4; ++i)
#pragma unroll
    for (int j = 0; j < 4; ++j)
#pragma unroll
      for (int e = 0; e < 4; ++e) acc[i][j][e] = 0.0f;

  for (int t = 0; t < KT; ++t) {
    const int kt = t * BK;
#pragma unroll
    for (int i = 0; i < 4; ++i) {
      gload_lds16(aSrc[i] + kt, lds + aDst[i]);
      gload_lds16(bSrc[i] + kt, lds + bDst[i]);
    }
    __syncthreads();  // drains vmcnt; tile landed for all waves

    bf16x8 af[4][2], bfr[4][2];
#pragma unroll
    for (int mi = 0; mi < 4; ++mi)
#pragma unroll
      for (int ks = 0; ks < 2; ++ks)
        af[mi][ks] =
            *reinterpret_cast<const bf16x8*>(lds + aBase[ks] + mi * 1024);
#pragma unroll
    for (int ni = 0; ni < 4; ++ni)
#pragma unroll
      for (int ks = 0; ks < 2; ++ks)
        bfr[ni][ks] =
            *reinterpret_cast<const bf16x8*>(lds + bBase[ks] + ni * 1024);
#pragma unroll
    for (int mi = 0; mi < 4; ++mi)
#pragma unroll
      for (int ni = 0; ni < 4; ++ni) {
        acc[mi][ni] = MFMA16(af[mi][0], bfr[ni][0], acc[mi][ni]);
        acc[mi][ni] = MFMA16(af[mi][1], bfr[ni][1], acc[mi][ni]);
      }
    __syncthreads();  // all reads done -> next stage may overwrite
  }

  // ---- write cur (bf16) via per-wave LDS transpose, coalesced ----
  float* swp = reinterpret_cast<float*>(lds) + wave * (16 * 66);
  const int er = lane >> 2;        // 0..15
  const int ec = (lane & 3) * 4;   // 0,4,8,12
#pragma unroll
  for (int mi = 0; mi < 4; ++mi) {
#pragma unroll
    for (int ni = 0; ni < 4; ++ni)
#pragma unroll
      for (int j = 0; j < 4; ++j)
        swp[(l4 * 4 + j) * 66 + ni * 16 + l15] = acc[mi][ni][j];
    // same-wave RAW on LDS: compiler inserts lgkmcnt wait

    const int row = m0 + wm * 64 + mi * 16 + er;
    const int colb = n0 + wn * 64 + ec;
    bf16_t* cr = cur + (size_t)row * N_DIM + colb;
#pragma unroll
    for (int cc = 0; cc < 4; ++cc) {
      const f32x4 av =
          *reinterpret_cast<const f32x4*>(swp + er * 66 + ec + cc * 16);
      bf16x4 o;
#pragma unroll
      for (int e = 0; e < 4; ++e) o[e] = (bf16_t)av[e];
      *reinterpret_cast<bf16x4*>(cr + cc * 16) = o;
    }
    __syncthreads();  // keep waves in step before slab reuse (cheap, 4x)
  }
}

// ---------------------------------------------------------------------------
// LIF epilogue, streaming regime: grid-stride over f32x4 chunks.
// next_I = a*I + cur + rec ; next_V = (b*V + next_I)*gate ; next_Z = step.
// rec/gate from compact spike list (Zin read only on dense fallback).
// ---------------------------------------------------------------------------
__global__ __launch_bounds__(256) void lif_epi(
    const bf16_t* __restrict__ cur, const float* __restrict__ recw,
    const int* __restrict__ zcnt, const int* __restrict__ zidx,
    const float* __restrict__ zval,
    const float* __restrict__ Iin, const float* __restrict__ Vin,
    const float* __restrict__ Zin,
    float* __restrict__ outZ, float* __restrict__ outI,
    float* __restrict__ outV) {
  const float alpha = 0.90483741803595957f;  // exp(-0.1)
  const float beta = 0.81873075307798182f;   // exp(-0.2)
  const int nthr = gridDim.x * 256;
  const int total = (M_DIM * N_DIM) / 4;  // 2^21 chunks

  for (int c = blockIdx.x * 256 + threadIdx.x; c < total; c += nthr) {
    const int row = c >> 9;            // N/4 = 512 chunks per row
    const int col = (c & 511) * 4;
    const size_t gb = (size_t)row * N_DIM + col;

    const bf16x4 cb = *reinterpret_cast<const bf16x4*>(cur + gb);
    const f32x4 iv = *reinterpret_cast<const f32x4*>(Iin + gb);
    const f32x4 vv = *reinterpret_cast<const f32x4*>(Vin + gb);

    f32x4 rec, gate;
#pragma unroll
    for (int e = 0; e < 4; ++e) {
      rec[e] = 0.0f;
      gate[e] = 1.0f;
    }
    const int cnt = zcnt[row];
    if (cnt > 0) {
      if (cnt <= ZCAP) {  // event-driven path (Zin untouched)
        const int* zi = zidx + (size_t)row * ZCAP;
        const float* zv = zval + (size_t)row * ZCAP;
        for (int s = 0; s < cnt; ++s) {
          const int o = zi[s];
          const float v = zv[s];
          const f32x4 wv =
              *reinterpret_cast<const f32x4*>(recw + (size_t)o * N_DIM + col);
#pragma unroll
          for (int e = 0; e < 4; ++e) {
            rec[e] += v * wv[e];
            gate[e] = (o == col + e) ? (1.0f - v) : gate[e];
          }
        }
      } else {  // dense fallback (general correctness; not taken here)
        const float* zr = Zin + (size_t)row * N_DIM;
        for (int o = 0; o < N_DIM; ++o) {
          const float v = zr[o];
          if (v != 0.0f) {
            const f32x4 wv = *reinterpret_cast<const f32x4*>(
                recw + (size_t)o * N_DIM + col);
#pragma unroll
            for (int e = 0; e < 4; ++e) {
              rec[e] += v * wv[e];
              gate[e] = (o == col + e) ? (1.0f - v) : gate[e];
            }
          }
        }
      }
    }

    f32x4 nI, nV, nZ;
#pragma unroll
    for (int e = 0; e < 4; ++e) {
      nI[e] = alpha * iv[e] + (float)cb[e] + rec[e];
      nV[e] = (beta * vv[e] + nI[e]) * gate[e];
      nZ[e] = (nV[e] > 1.0f) ? 1.0f : 0.0f;
    }
    *reinterpret_cast<f32x4*>(outI + gb) = nI;
    *reinterpret_cast<f32x4*>(outV + gb) = nV;
    *reinterpret_cast<f32x4*>(outZ + gb) = nZ;
  }
}

extern "C" void kernel_launch(void* const* d_in, const int* in_sizes, int n_in,
                              void* d_out, int out_size, void* d_ws,
                              size_t ws_size, hipStream_t stream) {
  const float* inputs = (const float*)d_in[0];
  const float* I = (const float*)d_in[1];
  const float* V = (const float*)d_in[2];
  const float* Z = (const float*)d_in[3];
  const float* fwd_w = (const float*)d_in[4];
  const float* rec_w = (const float*)d_in[5];

  float* outZ = (float*)d_out;
  float* outI = outZ + (size_t)M_DIM * N_DIM;
  float* outV = outI + (size_t)M_DIM * N_DIM;

  // ws: abf 16MiB | wT 8MiB | zcnt 16KiB | zidx 1MiB | zval 1MiB | cur 16MiB
  bf16_t* abf = (bf16_t*)d_ws;
  bf16_t* wT = (bf16_t*)((char*)d_ws + (size_t)M_DIM * K_DIM * 2);
  char* p = (char*)d_ws + (size_t)M_DIM * K_DIM * 2 + (size_t)N_DIM * K_DIM * 2;
  int* zcnt = (int*)p;
  int* zidx = (int*)(p + M_DIM * 4);
  float* zval = (float*)(p + M_DIM * 4 + (size_t)M_DIM * ZCAP * 4);
  bf16_t* curb = (bf16_t*)(p + M_DIM * 4 + (size_t)M_DIM * ZCAP * 8);

  hipLaunchKernelGGL(prepass_all, dim3(6144), dim3(256), 0, stream, inputs,
                     fwd_w, Z, abf, wT, zcnt, zidx, zval);
  hipLaunchKernelGGL(gemm_cur, dim3((M_DIM / BM) * (N_DIM / BN)), dim3(256), 0,
                     stream, abf, wT, curb);
  hipLaunchKernelGGL(lif_epi, dim3(2048), dim3(256), 0, stream, curb, rec_w,
                     zcnt, zidx, zval, I, V, Z, outZ, outI, outV);
}

// Round 10
// 84.740 us; speedup vs baseline: 1.1166x; 1.1166x over previous
//
#include <hip/hip_runtime.h>
#include <cstdint>
#include <cstddef>

typedef __bf16 bf16_t;
typedef __bf16 bf16x4 __attribute__((ext_vector_type(4)));
typedef __bf16 bf16x8 __attribute__((ext_vector_type(8)));
typedef float f32x4 __attribute__((ext_vector_type(4)));

#define M_DIM 4096
#define K_DIM 2048
#define N_DIM 2048

// ---- fwd GEMM geometry (R7, best measured): 128x128, BK=64, dbuf ----
#define BM 128
#define BN 128
#define BK 64
#define KT (K_DIM / BK)        // 32 K-tiles
#define A_EL (BM * BK)         // 8192 bf16 (16 KiB)
#define B_EL (BN * BK)         // 8192 bf16 (16 KiB)
#define PER_BUF (A_EL + B_EL)  // 32 KiB
#define B_OFF A_EL

#define ZCAP 64                // spikes kept per row; overflow -> dense path

#define MFMA16(a, b, c) \
  __builtin_amdgcn_mfma_f32_16x16x32_bf16((a), (b), (c), 0, 0, 0)

__device__ __forceinline__ void gload_lds16(const bf16_t* g, bf16_t* l) {
  __builtin_amdgcn_global_load_lds(
      (const __attribute__((address_space(1))) void*)g,
      (__attribute__((address_space(3))) void*)l, 16, 0, 0);
}

// ---------------------------------------------------------------------------
// Merged prepass: [0,4096) inputs f32->bf16; [4096,5120) transpose fwd_w;
// [5120,6144) scan Z into (cnt, idx, val) per row.
// ---------------------------------------------------------------------------
__global__ __launch_bounds__(256) void prepass_all(
    const float* __restrict__ inputs, const float* __restrict__ fwd_w,
    const float* __restrict__ Z, bf16_t* __restrict__ abf,
    bf16_t* __restrict__ wT, int* __restrict__ zcnt, int* __restrict__ zidx,
    float* __restrict__ zval) {
  __shared__ float tile[64][65];
  const int b = blockIdx.x;
  const int t = threadIdx.x;

  if (b < 4096) {  // ---- convert_a ----
    const size_t base = ((size_t)b * 256 + t) * 8;
    const float4 v0 = *reinterpret_cast<const float4*>(inputs + base);
    const float4 v1 = *reinterpret_cast<const float4*>(inputs + base + 4);
    bf16x8 o;
    o[0] = (bf16_t)v0.x; o[1] = (bf16_t)v0.y;
    o[2] = (bf16_t)v0.z; o[3] = (bf16_t)v0.w;
    o[4] = (bf16_t)v1.x; o[5] = (bf16_t)v1.y;
    o[6] = (bf16_t)v1.z; o[7] = (bf16_t)v1.w;
    *reinterpret_cast<bf16x8*>(abf + base) = o;
  } else if (b < 5120) {  // ---- transpose_w ----
    const int bb = b - 4096;
    const int n0 = (bb & 31) * 64;
    const int k0 = (bb >> 5) * 64;
#pragma unroll
    for (int p = 0; p < 4; ++p) {
      const int r = p * 16 + (t >> 4);
      const int c = (t & 15) * 4;
      const float4 v = *reinterpret_cast<const float4*>(
          &fwd_w[(size_t)(k0 + r) * N_DIM + n0 + c]);
      tile[r][c + 0] = v.x;
      tile[r][c + 1] = v.y;
      tile[r][c + 2] = v.z;
      tile[r][c + 3] = v.w;
    }
    __syncthreads();
#pragma unroll
    for (int p = 0; p < 4; ++p) {
      const int n = p * 16 + (t >> 4);
      const int c = (t & 15) * 4;
      bf16x4 o;
      o[0] = (bf16_t)tile[c + 0][n];
      o[1] = (bf16_t)tile[c + 1][n];
      o[2] = (bf16_t)tile[c + 2][n];
      o[3] = (bf16_t)tile[c + 3][n];
      *reinterpret_cast<bf16x4*>(&wT[(size_t)(n0 + n) * K_DIM + k0 + c]) = o;
    }
  } else {  // ---- scan_z ----
    const int row = (b - 5120) * 4 + (t >> 6);
    const int lane = t & 63;
    const float* zr = Z + (size_t)row * N_DIM;
    int local = 0;
#pragma unroll
    for (int c = 0; c < 32; c += 4) {
      const f32x4 v = *reinterpret_cast<const f32x4*>(zr + lane * 32 + c);
#pragma unroll
      for (int e = 0; e < 4; ++e) local += (v[e] != 0.0f) ? 1 : 0;
    }
    int pre = local;
#pragma unroll
    for (int d = 1; d < 64; d <<= 1) {
      const int up = __shfl_up(pre, d, 64);
      if (lane >= d) pre += up;
    }
    const int total = __shfl(pre, 63, 64);
    if (lane == 0) zcnt[row] = total;
    if (total > 0 && total <= ZCAP) {
      int wpos = pre - local;
      int* zi = zidx + (size_t)row * ZCAP;
      float* zv = zval + (size_t)row * ZCAP;
      for (int c = lane * 32; c < lane * 32 + 32; ++c) {
        const float v = zr[c];
        if (v != 0.0f) {
          zi[wpos] = c;
          zv[wpos] = v;
          ++wpos;
        }
      }
    }
  }
}

// ---------------------------------------------------------------------------
// Fused GEMM + sparse recurrent + LIF (R7, best measured). BM=BN=128, BK=64,
// 4 waves (2x2, 64x64/wave), double-buffered swizzled LDS, raw barriers,
// counted vmcnt. Vectorized epilogue via per-wave LDS transpose; Zin never
// read on the sparse path.
// ---------------------------------------------------------------------------
__global__ __launch_bounds__(256, 2) void lif_gemm_db(
    const bf16_t* __restrict__ A, const bf16_t* __restrict__ W,
    const float* __restrict__ recw,
    const int* __restrict__ zcnt, const int* __restrict__ zidx,
    const float* __restrict__ zval,
    const float* __restrict__ Iin, const float* __restrict__ Vin,
    const float* __restrict__ Zin,
    float* __restrict__ outZ, float* __restrict__ outI,
    float* __restrict__ outV) {
  __shared__ __align__(16) bf16_t lds[2 * PER_BUF];  // 64 KiB

  const int tid = threadIdx.x;
  const int lane = tid & 63;
  const int wave = tid >> 6;   // 0..3
  const int wm = wave >> 1;    // 0..1
  const int wn = wave & 1;     // 0..1
  const int l15 = lane & 15;
  const int l4 = lane >> 4;

  // T1: XCD swizzle (512 blocks, 512%8==0 -> bijective)
  const int bid = blockIdx.x;
  const int swz = (bid & 7) * 64 + (bid >> 3);
  const int m0 = (swz >> 4) * BM;  // 32 m-tiles
  const int n0 = (swz & 15) * BN;  // 16 n-tiles

  // ---- staging (pre-swizzled global source, linear LDS dest; rule 21) ----
  const int lr = lane >> 3;        // 0..7
  const int sg = (lane & 7) ^ lr;  // swizzled 16B-slot
  const bf16_t* aSrc[4];
  const bf16_t* bSrc[4];
  int aDst[4], bDst[4];
#pragma unroll
  for (int i = 0; i < 4; ++i) {
    const int r = wave * 32 + i * 8 + lr;  // rows 0..127
    aSrc[i] = A + (size_t)(m0 + r) * K_DIM + sg * 8;
    aDst[i] = r * BK + (lane & 7) * 8;
    bSrc[i] = W + (size_t)(n0 + r) * K_DIM + sg * 8;
    bDst[i] = B_OFF + r * BK + (lane & 7) * 8;
  }

  // ---- swizzled fragment read bases ----
  int aBase[2], bBase[2];
#pragma unroll
  for (int ks = 0; ks < 2; ++ks) {
    const int phys = (l4 + ks * 4) ^ (l15 & 7);
    aBase[ks] = (wm * 64 + l15) * BK + phys * 8;
    bBase[ks] = B_OFF + (wn * 64 + l15) * BK + phys * 8;
  }

  f32x4 acc[4][4];
#pragma unroll
  for (int i = 0; i < 4; ++i)
#pragma unroll
    for (int j = 0; j < 4; ++j)
#pragma unroll
      for (int e = 0; e < 4; ++e) acc[i][j][e] = 0.0f;

  // ---- prologue: stage tile 0 -> buf0, tile 1 -> buf1 ----
#pragma unroll
  for (int i = 0; i < 4; ++i) {
    gload_lds16(aSrc[i], lds + aDst[i]);
    gload_lds16(bSrc[i], lds + bDst[i]);
  }
#pragma unroll
  for (int i = 0; i < 4; ++i) {
    gload_lds16(aSrc[i] + BK, lds + PER_BUF + aDst[i]);
    gload_lds16(bSrc[i] + BK, lds + PER_BUF + bDst[i]);
  }
  asm volatile("s_waitcnt vmcnt(8)" ::: "memory");  // tile 0 landed (mine)
  __builtin_amdgcn_sched_barrier(0);
  __builtin_amdgcn_s_barrier();                     // everyone's tile 0
  __builtin_amdgcn_sched_barrier(0);

  for (int t = 0; t < KT; ++t) {
    const bf16_t* bufC = lds + (t & 1) * PER_BUF;
    bf16_t* bufS = lds + (t & 1) * PER_BUF;  // t+2 goes where t was

    // ---- ds_read all fragments of tile t ----
    bf16x8 af[4][2], bfr[4][2];
#pragma unroll
    for (int mi = 0; mi < 4; ++mi)
#pragma unroll
      for (int ks = 0; ks < 2; ++ks)
        af[mi][ks] =
            *reinterpret_cast<const bf16x8*>(bufC + aBase[ks] + mi * 1024);
#pragma unroll
    for (int ni = 0; ni < 4; ++ni)
#pragma unroll
      for (int ks = 0; ks < 2; ++ks)
        bfr[ni][ks] =
            *reinterpret_cast<const bf16x8*>(bufC + bBase[ks] + ni * 1024);
    asm volatile("s_waitcnt lgkmcnt(0)" ::: "memory");
    __builtin_amdgcn_sched_barrier(0);
    __builtin_amdgcn_s_barrier();  // all waves done reading buf[t&1]
    __builtin_amdgcn_sched_barrier(0);

    // ---- stage t+2 into buf[t&1] (now safe to overwrite) ----
    if (t + 2 < KT) {
      const int kt = (t + 2) * BK;
#pragma unroll
      for (int i = 0; i < 4; ++i) {
        gload_lds16(aSrc[i] + kt, bufS + aDst[i]);
        gload_lds16(bSrc[i] + kt, bufS + bDst[i]);
      }
    }

    // ---- MFMA tile t (hides t+1/t+2 flight) ----
    __builtin_amdgcn_s_setprio(1);
#pragma unroll
    for (int mi = 0; mi < 4; ++mi)
#pragma unroll
      for (int ni = 0; ni < 4; ++ni) {
        acc[mi][ni] = MFMA16(af[mi][0], bfr[ni][0], acc[mi][ni]);
        acc[mi][ni] = MFMA16(af[mi][1], bfr[ni][1], acc[mi][ni]);
      }
    __builtin_amdgcn_s_setprio(0);
    __builtin_amdgcn_sched_barrier(0);

    // ---- counted wait: tile t+1 landed; t+2's 8 loads stay in flight ----
    if (t + 2 < KT) {
      asm volatile("s_waitcnt vmcnt(8)" ::: "memory");
    } else if (t + 1 < KT) {
      asm volatile("s_waitcnt vmcnt(0)" ::: "memory");
    }
    __builtin_amdgcn_sched_barrier(0);
    __builtin_amdgcn_s_barrier();
    __builtin_amdgcn_sched_barrier(0);
  }

  // ==== epilogue: per-mi LDS transpose -> fully vectorized LIF ====
  const float alpha = 0.90483741803595957f;  // exp(-0.1)
  const float beta = 0.81873075307798182f;   // exp(-0.2)
  float* swp = reinterpret_cast<float*>(lds) + wave * (16 * 66);
  const int er = lane >> 2;            // 0..15 (row within 16-row slab)
  const int ec = (lane & 3) * 4;       // 0,4,8,12

#pragma unroll
  for (int mi = 0; mi < 4; ++mi) {
    // acc -> LDS (stride 66: 2-way max, free)
#pragma unroll
    for (int ni = 0; ni < 4; ++ni)
#pragma unroll
      for (int j = 0; j < 4; ++j)
        swp[(l4 * 4 + j) * 66 + ni * 16 + l15] = acc[mi][ni][j];
    // same-wave RAW on LDS: compiler inserts lgkmcnt wait

    const int row = m0 + wm * 64 + mi * 16 + er;
    const int colb = n0 + wn * 64 + ec;  // + cc*16
    const int cnt = zcnt[row];

    f32x4 rec4[4], gate4[4];
#pragma unroll
    for (int cc = 0; cc < 4; ++cc)
#pragma unroll
      for (int e = 0; e < 4; ++e) {
        rec4[cc][e] = 0.0f;
        gate4[cc][e] = 1.0f;
      }
    if (cnt > 0) {
      if (cnt <= ZCAP) {  // event-driven: Zin never touched
        const int* zi = zidx + (size_t)row * ZCAP;
        const float* zv = zval + (size_t)row * ZCAP;
        for (int s = 0; s < cnt; ++s) {
          const int o = zi[s];
          const float v = zv[s];
          const float* wr = recw + (size_t)o * N_DIM + colb;
#pragma unroll
          for (int cc = 0; cc < 4; ++cc) {
            const f32x4 wv = *reinterpret_cast<const f32x4*>(wr + cc * 16);
#pragma unroll
            for (int e = 0; e < 4; ++e) {
              rec4[cc][e] += v * wv[e];
              gate4[cc][e] = (o == colb + cc * 16 + e) ? (1.0f - v)
                                                       : gate4[cc][e];
            }
          }
        }
      } else {  // dense fallback (general correctness)
        const float* zr = Zin + (size_t)row * N_DIM;
        for (int o = 0; o < N_DIM; ++o) {
          const float v = zr[o];
          if (v != 0.0f) {
            const float* wr = recw + (size_t)o * N_DIM + colb;
#pragma unroll
            for (int cc = 0; cc < 4; ++cc) {
              const f32x4 wv = *reinterpret_cast<const f32x4*>(wr + cc * 16);
#pragma unroll
              for (int e = 0; e < 4; ++e) {
                rec4[cc][e] += v * wv[e];
                gate4[cc][e] = (o == colb + cc * 16 + e) ? (1.0f - v)
                                                         : gate4[cc][e];
              }
            }
          }
        }
      }
    }

    const size_t gb = (size_t)row * N_DIM + colb;
#pragma unroll
    for (int cc = 0; cc < 4; ++cc) {
      const f32x4 av =
          *reinterpret_cast<const f32x4*>(swp + er * 66 + ec + cc * 16);
      const f32x4 iv = *reinterpret_cast<const f32x4*>(Iin + gb + cc * 16);
      const f32x4 vv = *reinterpret_cast<const f32x4*>(Vin + gb + cc * 16);
      f32x4 nI, nV, nZ;
#pragma unroll
      for (int e = 0; e < 4; ++e) {
        nI[e] = alpha * iv[e] + av[e] + rec4[cc][e];
        nV[e] = (beta * vv[e] + nI[e]) * gate4[cc][e];
        nZ[e] = (nV[e] > 1.0f) ? 1.0f : 0.0f;
      }
      *reinterpret_cast<f32x4*>(outI + gb + cc * 16) = nI;
      *reinterpret_cast<f32x4*>(outV + gb + cc * 16) = nV;
      *reinterpret_cast<f32x4*>(outZ + gb + cc * 16) = nZ;
    }
    // next mi reuses this wave's private slab (same-wave ordering only)
  }
}

extern "C" void kernel_launch(void* const* d_in, const int* in_sizes, int n_in,
                              void* d_out, int out_size, void* d_ws,
                              size_t ws_size, hipStream_t stream) {
  const float* inputs = (const float*)d_in[0];
  const float* I = (const float*)d_in[1];
  const float* V = (const float*)d_in[2];
  const float* Z = (const float*)d_in[3];
  const float* fwd_w = (const float*)d_in[4];
  const float* rec_w = (const float*)d_in[5];

  float* outZ = (float*)d_out;
  float* outI = outZ + (size_t)M_DIM * N_DIM;
  float* outV = outI + (size_t)M_DIM * N_DIM;

  // ws: abf 16 MiB | wT 8 MiB | zcnt 16 KiB | zidx 1 MiB | zval 1 MiB
  bf16_t* abf = (bf16_t*)d_ws;
  bf16_t* wT = (bf16_t*)((char*)d_ws + (size_t)M_DIM * K_DIM * 2);
  char* p = (char*)d_ws + (size_t)M_DIM * K_DIM * 2 + (size_t)N_DIM * K_DIM * 2;
  int* zcnt = (int*)p;
  int* zidx = (int*)(p + M_DIM * 4);
  float* zval = (float*)(p + M_DIM * 4 + (size_t)M_DIM * ZCAP * 4);

  hipLaunchKernelGGL(prepass_all, dim3(6144), dim3(256), 0, stream, inputs,
                     fwd_w, Z, abf, wT, zcnt, zidx, zval);
  hipLaunchKernelGGL(lif_gemm_db, dim3((M_DIM / BM) * (N_DIM / BN)),
                     dim3(256), 0, stream, abf, wT, rec_w, zcnt, zidx, zval, I,
                     V, Z, outZ, outI, outV);
}